// Round 7
// baseline (87.049 us; speedup 1.0000x reference)
//
#include <hip/hip_runtime.h>

#define NN 65536
#define DD 8
#define LATD 64
#define HIDD 128
#define FEATD 16
#define SXS 72            // sX stride (u16): 144 B = 9 quads (odd -> conflict-free)
#define SHS 136           // sH stride (u16): 272 B = 17 quads (odd -> conflict-free)

typedef __attribute__((ext_vector_type(8))) short short8;
typedef __attribute__((ext_vector_type(4))) float f32x4;

static __device__ __forceinline__ unsigned short f2bf(float f) {
  union { float f; unsigned u; } v; v.f = f;
  unsigned r = v.u + 0x7FFFu + ((v.u >> 16) & 1u);  // RNE; exact for small ints
  return (unsigned short)(r >> 16);
}

static __device__ __forceinline__ short8 msk(short8 v, bool p) {
  short8 z = {0, 0, 0, 0, 0, 0, 0, 0};
  return p ? v : z;  // 4x v_cndmask_b32
}

// ---- prep: bf16-transpose the scales to [d][n][k]; reciprocal of div ------
__global__ __launch_bounds__(256) void k_prep(
    const float* __restrict__ s0, const float* __restrict__ s1,
    const float* __restrict__ s2, const float* __restrict__ divv,
    unsigned short* __restrict__ g0, unsigned short* __restrict__ g1,
    unsigned short* __restrict__ g2, float* __restrict__ rdiv) {
  int o = blockIdx.x * 256 + threadIdx.x;
  if (o < DD * HIDD * LATD) {            // g0[d][n(128)][k(64)] <- s0[d][k][n]
    int d = o >> 13, rem = o & 8191, n = rem >> 6, k = rem & 63;
    g0[o] = f2bf(s0[d * 8192 + k * 128 + n]);
  }
  if (o < DD * HIDD * HIDD) {            // g1[d][n(128)][k(128)] <- s1[d][k][n]
    int d = o >> 14, rem = o & 16383, n = rem >> 7, k = rem & 127;
    g1[o] = f2bf(s1[d * 16384 + k * 128 + n]);
  }
  if (o < DD * FEATD * HIDD) {           // g2[d][n(16)][k(128)] <- s2[d][k][n]
    int d = o >> 11, rem = o & 2047, n = rem >> 7, k = rem & 127;
    g2[o] = f2bf(s2[d * 2048 + k * 16 + n]);
  }
  if (o < LATD) rdiv[o] = 1.0f / divv[o];
}

// ---- one-pass: 64 consecutive entries per block, all-decoder MFMA with ----
// accumulator-merge (masked A rows). No sort, no scatter, no gather.
// 4 waves: wave w owns col-blocks {2w,2w+1} (L1/L2) and row-strip w (L3).
__global__ __launch_bounds__(256, 3) void k_onepass(
    const float* __restrict__ weight, const float* __restrict__ ap,
    const float* __restrict__ rdiv,
    const unsigned short* __restrict__ g0, const float* __restrict__ sh0,
    const unsigned short* __restrict__ g1, const float* __restrict__ sh1,
    const unsigned short* __restrict__ g2, const float* __restrict__ sh2,
    float* __restrict__ out) {
  __shared__ unsigned short sX[64 * SXS];   // X  [row][k=64]
  __shared__ unsigned short sH1[64 * SHS];  // H1 [row][k=128]
  __shared__ unsigned short sH2[64 * SHS];  // H2 [row][k=128]
  __shared__ unsigned char sIdx[64];        // per-row argmax decoder

  int base = blockIdx.x * 64;
  int t = threadIdx.x;
  int w = t >> 6, l = t & 63;
  int lrow = l & 15, kgrp = l >> 4;

  // ---- argmax decoder per row (threads 0..63) ----
  if (t < 64) {
    int n = base + t;
    float best = ap[n];
    int bd = 0;
#pragma unroll
    for (int d = 1; d < DD; ++d) {
      float v = ap[d * NN + n];
      if (v > best) { best = v; bd = d; }  // strict >: first max (jnp.argmax)
    }
    sIdx[t] = (unsigned char)bd;
  }

  // ---- stage X = rint(weight)*rdiv, coalesced (4 threads per row) ----
  {
    int r = t >> 2, c = t & 3;
    const float* wr = weight + (base + r) * LATD + c * 16;
    const float* rd = rdiv + c * 16;
    short8 lo8, hi8;
#pragma unroll
    for (int q = 0; q < 2; ++q) {
      float4 f = *(const float4*)(wr + q * 4);
      float4 g = *(const float4*)(rd + q * 4);
      lo8[q * 4 + 0] = (short)f2bf(rintf(f.x) * g.x);
      lo8[q * 4 + 1] = (short)f2bf(rintf(f.y) * g.y);
      lo8[q * 4 + 2] = (short)f2bf(rintf(f.z) * g.z);
      lo8[q * 4 + 3] = (short)f2bf(rintf(f.w) * g.w);
    }
#pragma unroll
    for (int q = 0; q < 2; ++q) {
      float4 f = *(const float4*)(wr + 8 + q * 4);
      float4 g = *(const float4*)(rd + 8 + q * 4);
      hi8[q * 4 + 0] = (short)f2bf(rintf(f.x) * g.x);
      hi8[q * 4 + 1] = (short)f2bf(rintf(f.y) * g.y);
      hi8[q * 4 + 2] = (short)f2bf(rintf(f.z) * g.z);
      hi8[q * 4 + 3] = (short)f2bf(rintf(f.w) * g.w);
    }
    *(short8*)&sX[r * SXS + c * 16] = lo8;
    *(short8*)&sX[r * SXS + c * 16 + 8] = hi8;
  }
  __syncthreads();

  // per-lane A-row decoders (A row = lrow) and D-row decoders (rows kgrp*4+rr)
  int arow[4], dec16[4][4];
#pragma unroll
  for (int rg = 0; rg < 4; ++rg) {
    arow[rg] = sIdx[rg * 16 + lrow];
#pragma unroll
    for (int rr = 0; rr < 4; ++rr) dec16[rg][rr] = sIdx[rg * 16 + kgrp * 4 + rr];
  }

  // ---- layer 1: [64]->[128] relu, accumulator-merge over decoders ----
  short8 xa[4][2];
#pragma unroll
  for (int rg = 0; rg < 4; ++rg) {
    xa[rg][0] = *(short8*)&sX[(rg * 16 + lrow) * SXS + kgrp * 8];
    xa[rg][1] = *(short8*)&sX[(rg * 16 + lrow) * SXS + 32 + kgrp * 8];
  }
  {
    f32x4 acc[4][2];
#pragma unroll
    for (int rg = 0; rg < 4; ++rg)
#pragma unroll
      for (int cb = 0; cb < 2; ++cb)
#pragma unroll
        for (int rr = 0; rr < 4; ++rr)
          acc[rg][cb][rr] = sh0[dec16[rg][rr] * HIDD + (2 * w + cb) * 16 + lrow];

    for (int d = 0; d < DD; ++d) {
      const unsigned short* G0 = g0 + d * (HIDD * LATD);
      short8 b[2][2];
#pragma unroll
      for (int cb = 0; cb < 2; ++cb)
#pragma unroll
        for (int ks = 0; ks < 2; ++ks)
          b[cb][ks] = *(const short8*)&G0[((2 * w + cb) * 16 + lrow) * LATD + ks * 32 + kgrp * 8];
#pragma unroll
      for (int rg = 0; rg < 4; ++rg) {
        bool p = (arow[rg] == d);
        short8 a0 = msk(xa[rg][0], p), a1 = msk(xa[rg][1], p);
#pragma unroll
        for (int cb = 0; cb < 2; ++cb) {
          acc[rg][cb] = __builtin_amdgcn_mfma_f32_16x16x32_bf16(a0, b[cb][0], acc[rg][cb], 0, 0, 0);
          acc[rg][cb] = __builtin_amdgcn_mfma_f32_16x16x32_bf16(a1, b[cb][1], acc[rg][cb], 0, 0, 0);
        }
      }
    }
#pragma unroll
    for (int rg = 0; rg < 4; ++rg)
#pragma unroll
      for (int cb = 0; cb < 2; ++cb)
#pragma unroll
        for (int rr = 0; rr < 4; ++rr)
          sH1[(rg * 16 + kgrp * 4 + rr) * SHS + (2 * w + cb) * 16 + lrow] =
              f2bf(fmaxf(acc[rg][cb][rr], 0.f));
  }
  __syncthreads();

  // ---- layer 2: [128]->[128] relu ----
  {
    short8 ha[4][4];
#pragma unroll
    for (int rg = 0; rg < 4; ++rg)
#pragma unroll
      for (int s = 0; s < 4; ++s)
        ha[rg][s] = *(short8*)&sH1[(rg * 16 + lrow) * SHS + s * 32 + kgrp * 8];

    f32x4 acc[4][2];
#pragma unroll
    for (int rg = 0; rg < 4; ++rg)
#pragma unroll
      for (int cb = 0; cb < 2; ++cb)
#pragma unroll
        for (int rr = 0; rr < 4; ++rr)
          acc[rg][cb][rr] = sh1[dec16[rg][rr] * HIDD + (2 * w + cb) * 16 + lrow];

    for (int d = 0; d < DD; ++d) {
      const unsigned short* G1 = g1 + d * (HIDD * HIDD);
      short8 b[2][4];
#pragma unroll
      for (int cb = 0; cb < 2; ++cb)
#pragma unroll
        for (int ks = 0; ks < 4; ++ks)
          b[cb][ks] = *(const short8*)&G1[((2 * w + cb) * 16 + lrow) * HIDD + ks * 32 + kgrp * 8];
#pragma unroll
      for (int rg = 0; rg < 4; ++rg) {
        bool p = (arow[rg] == d);
#pragma unroll
        for (int cb = 0; cb < 2; ++cb) {
#pragma unroll
          for (int s = 0; s < 4; ++s)
            acc[rg][cb] = __builtin_amdgcn_mfma_f32_16x16x32_bf16(msk(ha[rg][s], p), b[cb][s], acc[rg][cb], 0, 0, 0);
        }
      }
    }
#pragma unroll
    for (int rg = 0; rg < 4; ++rg)
#pragma unroll
      for (int cb = 0; cb < 2; ++cb)
#pragma unroll
        for (int rr = 0; rr < 4; ++rr)
          sH2[(rg * 16 + kgrp * 4 + rr) * SHS + (2 * w + cb) * 16 + lrow] =
              f2bf(fmaxf(acc[rg][cb][rr], 0.f));
  }
  __syncthreads();

  // ---- layer 3: [128]->[16], row-strip = wave, coalesced store ----
  {
    short8 qa[4];
#pragma unroll
    for (int s = 0; s < 4; ++s)
      qa[s] = *(short8*)&sH2[(w * 16 + lrow) * SHS + s * 32 + kgrp * 8];
    int a3 = sIdx[w * 16 + lrow];
    f32x4 acc;
#pragma unroll
    for (int rr = 0; rr < 4; ++rr)
      acc[rr] = sh2[sIdx[w * 16 + kgrp * 4 + rr] * FEATD + lrow];

    for (int d = 0; d < DD; ++d) {
      const unsigned short* G2 = g2 + d * (FEATD * HIDD);
      short8 b[4];
#pragma unroll
      for (int ks = 0; ks < 4; ++ks)
        b[ks] = *(const short8*)&G2[lrow * HIDD + ks * 32 + kgrp * 8];
      bool p = (a3 == d);
#pragma unroll
      for (int ks = 0; ks < 4; ++ks)
        acc = __builtin_amdgcn_mfma_f32_16x16x32_bf16(msk(qa[ks], p), b[ks], acc, 0, 0, 0);
    }
#pragma unroll
    for (int rr = 0; rr < 4; ++rr)
      out[(base + w * 16 + kgrp * 4 + rr) * FEATD + lrow] = acc[rr];
  }
}

// ---------------------------------------------------------------------------
extern "C" void kernel_launch(void* const* d_in, const int* in_sizes, int n_in,
                              void* d_out, int out_size, void* d_ws, size_t ws_size,
                              hipStream_t stream) {
  const float* weight      = (const float*)d_in[0];
  const float* alpha_param = (const float*)d_in[1];
  const float* divv        = (const float*)d_in[2];
  const float* scale0      = (const float*)d_in[3];
  const float* shift0      = (const float*)d_in[4];
  const float* scale1      = (const float*)d_in[5];
  const float* shift1      = (const float*)d_in[6];
  const float* scale2      = (const float*)d_in[7];
  const float* shift2      = (const float*)d_in[8];
  float* out = (float*)d_out;

  float* rdiv = (float*)d_ws;                              // [64]
  unsigned short* g0 = (unsigned short*)(rdiv + 64);       // [8][128][64]
  unsigned short* g1 = g0 + DD * HIDD * LATD;              // [8][128][128]
  unsigned short* g2 = g1 + DD * HIDD * HIDD;              // [8][16][128]

  k_prep<<<512, 256, 0, stream>>>(scale0, scale1, scale2, divv, g0, g1, g2, rdiv);
  k_onepass<<<NN / 64, 256, 0, stream>>>(weight, alpha_param, rdiv,
                                         g0, shift0, g1, shift1, g2, shift2, out);
}

// Round 8
// 70.248 us; speedup vs baseline: 1.2392x; 1.2392x over previous
//
#include <hip/hip_runtime.h>

#define NN 65536
#define DD 8
#define LATD 64
#define HIDD 128
#define FEATD 16
#define BPD 192           // k_mlp blocks per decoder (1536 total = 6/CU)
#define TILE 32
#define SXS 72            // sX stride (u16): 144 B = 9 quads (odd -> conflict-free)
#define SHS 136           // sH stride (u16): 272 B = 17 quads (odd -> conflict-free)

typedef __attribute__((ext_vector_type(8))) short short8;
typedef __attribute__((ext_vector_type(4))) float f32x4;

static __device__ __forceinline__ unsigned short f2bf(float f) {
  union { float f; unsigned u; } v; v.f = f;
  unsigned r = v.u + 0x7FFFu + ((v.u >> 16) & 1u);  // RNE; exact for small ints
  return (unsigned short)(r >> 16);
}

// ---- prep: blocks [0,256) bucket entries -> perm; [256,768) convert scales -
__global__ __launch_bounds__(256) void k_prep(
    const float* __restrict__ ap, int* __restrict__ cursor,
    unsigned short* __restrict__ perm,
    const float* __restrict__ s0, const float* __restrict__ s1,
    const float* __restrict__ s2, const float* __restrict__ divv,
    unsigned short* __restrict__ g0, unsigned short* __restrict__ g1,
    unsigned short* __restrict__ g2, float* __restrict__ rdiv) {
  int bid = blockIdx.x;
  int t = threadIdx.x;
  if (bid < 256) {
    __shared__ int bc[DD];
    __shared__ int bbase[DD];
    if (t < DD) bc[t] = 0;
    __syncthreads();
    int n = bid * 256 + t;
    float best = ap[n];
    int bd = 0;
#pragma unroll
    for (int d = 1; d < DD; ++d) {
      float v = ap[d * NN + n];
      if (v > best) { best = v; bd = d; }  // strict >: first max (jnp.argmax)
    }
    int lr = atomicAdd(&bc[bd], 1);
    __syncthreads();
    if (t < DD) bbase[t] = atomicAdd(&cursor[t], bc[t]);
    __syncthreads();
    perm[bd * NN + bbase[bd] + lr] = (unsigned short)n;
  } else {
    int o = (bid - 256) * 256 + t;
    if (o < DD * HIDD * LATD) {            // g0[d][n(128)][k(64)] <- s0[d][k][n]
      int d = o >> 13, rem = o & 8191, n = rem >> 6, k = rem & 63;
      g0[o] = f2bf(s0[d * 8192 + k * 128 + n]);
    }
    if (o < DD * HIDD * HIDD) {            // g1[d][n(128)][k(128)] <- s1[d][k][n]
      int d = o >> 14, rem = o & 16383, n = rem >> 7, k = rem & 127;
      g1[o] = f2bf(s1[d * 16384 + k * 128 + n]);
    }
    if (o < DD * FEATD * HIDD) {           // g2[d][n(16)][k(128)] <- s2[d][k][n]
      int d = o >> 11, rem = o & 2047, n = rem >> 7, k = rem & 127;
      g2[o] = f2bf(s2[d * 2048 + k * 16 + n]);
    }
    if (o < LATD) rdiv[o] = 1.0f / divv[o];
  }
}

// ---- bucketed MFMA MLP, 32-row tiles, 6 blocks/CU --------------------------
// 256 thr = 4 waves. Waves split the 128 output cols as col-blocks {2w,2w+1}
// for L1/L2; L3 (16 cols) handled by waves 0,1 (row strips 0,1).
__global__ __launch_bounds__(256, 6) void k_mlp(
    const float* __restrict__ weight, const float* __restrict__ rdiv,
    const unsigned short* __restrict__ g0, const float* __restrict__ sh0,
    const unsigned short* __restrict__ g1, const float* __restrict__ sh1,
    const unsigned short* __restrict__ g2, const float* __restrict__ sh2,
    const int* __restrict__ cursor, const unsigned short* __restrict__ perm,
    float* __restrict__ out) {
  __shared__ unsigned short sX[TILE * SXS];   // X  [row][k=64]
  __shared__ unsigned short sH1[TILE * SHS];  // H1 [row][k=128]
  __shared__ unsigned short sH2[TILE * SHS];  // H2 [row][k=128]
  __shared__ unsigned short sP[TILE];         // entry ids for current tile

  int d = blockIdx.x / BPD, bslot = blockIdx.x % BPD;
  int cnt = cursor[d];
  int t = threadIdx.x;
  int w = t >> 6, l = t & 63;
  int lrow = l & 15, kgrp = l >> 4;

  // ---- B fragments, contiguous bf16, once per block ----
  short8 b0[2][2];  // [cb][ks] layer1 (k=64)
  short8 b1[2][4];  // [cb][ks] layer2 (k=128)
  short8 b2[4];     // [ks]     layer3 (k=128, 16 cols)
  float sh0v[2], sh1v[2];
  {
    const unsigned short* G0 = g0 + d * (HIDD * LATD);
    const unsigned short* G1 = g1 + d * (HIDD * HIDD);
    const unsigned short* G2 = g2 + d * (FEATD * HIDD);
#pragma unroll
    for (int cb = 0; cb < 2; ++cb) {
      int n2 = (2 * w + cb) * 16 + lrow;
#pragma unroll
      for (int ks = 0; ks < 2; ++ks)
        b0[cb][ks] = *(const short8*)&G0[n2 * LATD + ks * 32 + kgrp * 8];
#pragma unroll
      for (int ks = 0; ks < 4; ++ks)
        b1[cb][ks] = *(const short8*)&G1[n2 * HIDD + ks * 32 + kgrp * 8];
      sh0v[cb] = sh0[d * HIDD + n2];
      sh1v[cb] = sh1[d * HIDD + n2];
    }
#pragma unroll
    for (int ks = 0; ks < 4; ++ks)
      b2[ks] = *(const short8*)&G2[lrow * HIDD + ks * 32 + kgrp * 8];
  }
  float sh2v = sh2[d * FEATD + lrow];

  for (int tile = bslot; tile * TILE < cnt; tile += BPD) {
    int base = tile * TILE;

    // ---- stage X = rint(weight)*rdiv (8 threads per row, coalesced) ----
    {
      int r = t >> 3, c = t & 7;
      int gp = base + r;
      unsigned short pe = 0;
      short8 v8 = {0, 0, 0, 0, 0, 0, 0, 0};
      if (gp < cnt) {
        pe = perm[d * NN + gp];
        const float* wr = weight + (int)pe * LATD + c * 8;
        const float* rd = rdiv + c * 8;
        float4 f0 = *(const float4*)wr;
        float4 f1 = *(const float4*)(wr + 4);
        float4 q0 = *(const float4*)rd;
        float4 q1 = *(const float4*)(rd + 4);
        v8[0] = (short)f2bf(rintf(f0.x) * q0.x);
        v8[1] = (short)f2bf(rintf(f0.y) * q0.y);
        v8[2] = (short)f2bf(rintf(f0.z) * q0.z);
        v8[3] = (short)f2bf(rintf(f0.w) * q0.w);
        v8[4] = (short)f2bf(rintf(f1.x) * q1.x);
        v8[5] = (short)f2bf(rintf(f1.y) * q1.y);
        v8[6] = (short)f2bf(rintf(f1.z) * q1.z);
        v8[7] = (short)f2bf(rintf(f1.w) * q1.w);
      }
      if (c == 0) sP[r] = pe;
      *(short8*)&sX[r * SXS + c * 8] = v8;
    }
    __syncthreads();

    // L3 store rows (waves 0,1 only; cached to regs before sP is rewritten)
    int prow[4] = {0, 0, 0, 0};
    if (w < 2) {
#pragma unroll
      for (int rr = 0; rr < 4; ++rr) prow[rr] = (int)sP[w * 16 + kgrp * 4 + rr];
    }

    // ---- layer 1: [64]->[128] relu, sX -> sH1 ----
#pragma unroll
    for (int rg = 0; rg < 2; ++rg) {
      short8 a0 = *(short8*)&sX[(rg * 16 + lrow) * SXS + kgrp * 8];
      short8 a1 = *(short8*)&sX[(rg * 16 + lrow) * SXS + 32 + kgrp * 8];
#pragma unroll
      for (int cb = 0; cb < 2; ++cb) {
        f32x4 acc = {sh0v[cb], sh0v[cb], sh0v[cb], sh0v[cb]};
        acc = __builtin_amdgcn_mfma_f32_16x16x32_bf16(a0, b0[cb][0], acc, 0, 0, 0);
        acc = __builtin_amdgcn_mfma_f32_16x16x32_bf16(a1, b0[cb][1], acc, 0, 0, 0);
#pragma unroll
        for (int rr = 0; rr < 4; ++rr)
          sH1[(rg * 16 + kgrp * 4 + rr) * SHS + (2 * w + cb) * 16 + lrow] =
              f2bf(fmaxf(acc[rr], 0.f));
      }
    }
    __syncthreads();

    // ---- layer 2: [128]->[128] relu, sH1 -> sH2 ----
#pragma unroll
    for (int rg = 0; rg < 2; ++rg) {
      short8 h0 = *(short8*)&sH1[(rg * 16 + lrow) * SHS + kgrp * 8];
      short8 h1 = *(short8*)&sH1[(rg * 16 + lrow) * SHS + 32 + kgrp * 8];
      short8 h2 = *(short8*)&sH1[(rg * 16 + lrow) * SHS + 64 + kgrp * 8];
      short8 h3 = *(short8*)&sH1[(rg * 16 + lrow) * SHS + 96 + kgrp * 8];
#pragma unroll
      for (int cb = 0; cb < 2; ++cb) {
        f32x4 acc = {sh1v[cb], sh1v[cb], sh1v[cb], sh1v[cb]};
        acc = __builtin_amdgcn_mfma_f32_16x16x32_bf16(h0, b1[cb][0], acc, 0, 0, 0);
        acc = __builtin_amdgcn_mfma_f32_16x16x32_bf16(h1, b1[cb][1], acc, 0, 0, 0);
        acc = __builtin_amdgcn_mfma_f32_16x16x32_bf16(h2, b1[cb][2], acc, 0, 0, 0);
        acc = __builtin_amdgcn_mfma_f32_16x16x32_bf16(h3, b1[cb][3], acc, 0, 0, 0);
#pragma unroll
        for (int rr = 0; rr < 4; ++rr)
          sH2[(rg * 16 + kgrp * 4 + rr) * SHS + (2 * w + cb) * 16 + lrow] =
              f2bf(fmaxf(acc[rr], 0.f));
      }
    }
    __syncthreads();

    // ---- layer 3: [128]->[16], waves 0,1 own row strips 0,1 ----
    if (w < 2) {
      short8 q0 = *(short8*)&sH2[(w * 16 + lrow) * SHS + kgrp * 8];
      short8 q1 = *(short8*)&sH2[(w * 16 + lrow) * SHS + 32 + kgrp * 8];
      short8 q2 = *(short8*)&sH2[(w * 16 + lrow) * SHS + 64 + kgrp * 8];
      short8 q3 = *(short8*)&sH2[(w * 16 + lrow) * SHS + 96 + kgrp * 8];
      f32x4 acc = {sh2v, sh2v, sh2v, sh2v};
      acc = __builtin_amdgcn_mfma_f32_16x16x32_bf16(q0, b2[0], acc, 0, 0, 0);
      acc = __builtin_amdgcn_mfma_f32_16x16x32_bf16(q1, b2[1], acc, 0, 0, 0);
      acc = __builtin_amdgcn_mfma_f32_16x16x32_bf16(q2, b2[2], acc, 0, 0, 0);
      acc = __builtin_amdgcn_mfma_f32_16x16x32_bf16(q3, b2[3], acc, 0, 0, 0);
#pragma unroll
      for (int rr = 0; rr < 4; ++rr) {
        int row = w * 16 + kgrp * 4 + rr;
        if (base + row < cnt) out[prow[rr] * FEATD + lrow] = acc[rr];
      }
    }
    // no trailing barrier needed: next stage touches only sX/sP, which no
    // wave reads after its pre-L1 register loads (prow/A-frags), and the
    // next barrier1 orders the new sX/sP for everyone.
  }
}

// ---------------------------------------------------------------------------
extern "C" void kernel_launch(void* const* d_in, const int* in_sizes, int n_in,
                              void* d_out, int out_size, void* d_ws, size_t ws_size,
                              hipStream_t stream) {
  const float* weight      = (const float*)d_in[0];
  const float* alpha_param = (const float*)d_in[1];
  const float* divv        = (const float*)d_in[2];
  const float* scale0      = (const float*)d_in[3];
  const float* shift0      = (const float*)d_in[4];
  const float* scale1      = (const float*)d_in[5];
  const float* shift1      = (const float*)d_in[6];
  const float* scale2      = (const float*)d_in[7];
  const float* shift2      = (const float*)d_in[8];
  float* out = (float*)d_out;

  int* cursor = (int*)d_ws;                                    // [8]
  float* rdiv = (float*)(cursor + 16);                         // [64]
  unsigned short* perm = (unsigned short*)(rdiv + 64);         // [8][N]
  unsigned short* g0 = perm + DD * NN;                         // [8][128][64]
  unsigned short* g1 = g0 + DD * HIDD * LATD;                  // [8][128][128]
  unsigned short* g2 = g1 + DD * HIDD * HIDD;                  // [8][16][128]

  hipMemsetAsync(cursor, 0, DD * sizeof(int), stream);
  k_prep<<<768, 256, 0, stream>>>(alpha_param, cursor, perm,
                                  scale0, scale1, scale2, divv,
                                  g0, g1, g2, rdiv);
  k_mlp<<<DD * BPD, 256, 0, stream>>>(weight, rdiv,
                                      g0, shift0, g1, shift1, g2, shift2,
                                      cursor, perm, out);
}

// Round 10
// 62.324 us; speedup vs baseline: 1.3967x; 1.1271x over previous
//
#include <hip/hip_runtime.h>

#define NN 65536
#define DD 8
#define LATD 64
#define HIDD 128
#define FEATD 16
#define BPD 96            // k_mlp blocks per decoder (768 total = 3/CU)
#define REP 5             // DIAGNOSTIC: repeat tile loop 5x (idempotent, identical
                          // output each pass) so k_mlp exceeds the ~40us harness
                          // fills and appears in rocprof top-5 WITH counters.
                          // R11 removes this once the bottleneck is identified.
#define SXS 72            // sX stride (u16): 144 B = 9 quads (odd -> conflict-free)
#define SHS 136           // sH stride (u16): 272 B = 17 quads (odd -> conflict-free)

typedef __attribute__((ext_vector_type(8))) short short8;
typedef __attribute__((ext_vector_type(4))) float f32x4;

static __device__ __forceinline__ unsigned short f2bf(float f) {
  union { float f; unsigned u; } v; v.f = f;
  unsigned r = v.u + 0x7FFFu + ((v.u >> 16) & 1u);  // RNE; exact for small ints
  return (unsigned short)(r >> 16);
}

// ---- bucket: argmax over D + scatter into per-decoder perm lists ----------
__global__ __launch_bounds__(256) void k_bucket(const float* __restrict__ ap,
                                                int* __restrict__ cursor,
                                                unsigned short* __restrict__ perm) {
  __shared__ int bc[DD];
  __shared__ int bbase[DD];
  int t = threadIdx.x;
  if (t < DD) bc[t] = 0;
  __syncthreads();
  int n = blockIdx.x * 256 + t;
  float best = ap[n];
  int bd = 0;
#pragma unroll
  for (int d = 1; d < DD; ++d) {
    float v = ap[d * NN + n];
    if (v > best) { best = v; bd = d; }  // strict >: first max (jnp.argmax)
  }
  int lr = atomicAdd(&bc[bd], 1);
  __syncthreads();
  if (t < DD) bbase[t] = atomicAdd(&cursor[t], bc[t]);
  __syncthreads();
  perm[bd * NN + bbase[bd] + lr] = (unsigned short)n;
}

// ---- fused 3-layer MLP: B-fragments in registers (from fp32), H via LDS ---
// Exact bench-R3 champion body (30.3us, replay-stable) + trailing barrier.
// 256 thr = 4 waves; tile = 64 entries. Wave w owns output col-blocks
// {2w, 2w+1} (16 cols each) for L1/L2; L3 row-group = w.
__global__ __launch_bounds__(256, 3) void k_mlp(
    const float* __restrict__ weight, const float* __restrict__ divv,
    const float* __restrict__ s0, const float* __restrict__ sh0,
    const float* __restrict__ s1, const float* __restrict__ sh1,
    const float* __restrict__ s2, const float* __restrict__ sh2,
    const int* __restrict__ cursor, const unsigned short* __restrict__ perm,
    float* __restrict__ out) {
  __shared__ unsigned short sX[64 * SXS];   // X  [entry][k=64] bf16
  __shared__ unsigned short sH1[64 * SHS];  // H1 [entry][k=128] bf16
  __shared__ unsigned short sH2[64 * SHS];  // H2 [entry][k=128] bf16
  __shared__ unsigned short sP[64];         // perm cache for this tile

  int d = blockIdx.x / BPD, bslot = blockIdx.x % BPD;
  int cnt = cursor[d];
  int t = threadIdx.x;
  int w = t >> 6, l = t & 63;
  int lrow = l & 15, kgrp = l >> 4;

  // ---- load B fragments (fp32 global -> bf16 regs), once per block ----
  short8 b0[2][2];  // [cb][ks] layer1 (k=64)
  short8 b1[2][4];  // [cb][ks] layer2 (k=128)
  short8 b2[4];     // [ks]     layer3 (k=128, 16 cols)
  float sh0v[2], sh1v[2];
  const float* S0 = s0 + d * LATD * HIDD;
  const float* S1 = s1 + d * HIDD * HIDD;
  const float* S2 = s2 + d * HIDD * FEATD;
#pragma unroll
  for (int cb = 0; cb < 2; ++cb) {
    int n = (2 * w + cb) * 16 + lrow;
#pragma unroll
    for (int ks = 0; ks < 2; ++ks) {
      short8 v;
#pragma unroll
      for (int j = 0; j < 8; ++j)
        v[j] = (short)f2bf(S0[(ks * 32 + kgrp * 8 + j) * HIDD + n]);
      b0[cb][ks] = v;
    }
#pragma unroll
    for (int ks = 0; ks < 4; ++ks) {
      short8 v;
#pragma unroll
      for (int j = 0; j < 8; ++j)
        v[j] = (short)f2bf(S1[(ks * 32 + kgrp * 8 + j) * HIDD + n]);
      b1[cb][ks] = v;
    }
    sh0v[cb] = sh0[d * HIDD + n];
    sh1v[cb] = sh1[d * HIDD + n];
  }
#pragma unroll
  for (int ks = 0; ks < 4; ++ks) {
    short8 v;
#pragma unroll
    for (int j = 0; j < 8; ++j)
      v[j] = (short)f2bf(S2[(ks * 32 + kgrp * 8 + j) * FEATD + lrow]);
    b2[ks] = v;
  }
  float sh2v = sh2[d * FEATD + lrow];

  for (int rep = 0; rep < REP; ++rep) {
  for (int tile = bslot; tile * 64 < cnt; tile += BPD) {
    int base = tile * 64;

    // ---- stage X = rint(weight)/div into sX (4 threads per entry row) ----
    {
      int r = t >> 2, c = t & 3;
      int gp = base + r;
      unsigned short pe = 0;
      short8 lo = {0, 0, 0, 0, 0, 0, 0, 0}, hi = {0, 0, 0, 0, 0, 0, 0, 0};
      if (gp < cnt) {
        pe = perm[d * NN + gp];
        const float* wr = weight + (int)pe * LATD + c * 16;
        const float* dv = divv + c * 16;
#pragma unroll
        for (int q = 0; q < 2; ++q) {
          float4 f = *(const float4*)(wr + q * 4);
          float4 g = *(const float4*)(dv + q * 4);
          lo[q * 4 + 0] = (short)f2bf(rintf(f.x) / g.x);
          lo[q * 4 + 1] = (short)f2bf(rintf(f.y) / g.y);
          lo[q * 4 + 2] = (short)f2bf(rintf(f.z) / g.z);
          lo[q * 4 + 3] = (short)f2bf(rintf(f.w) / g.w);
        }
#pragma unroll
        for (int q = 0; q < 2; ++q) {
          float4 f = *(const float4*)(wr + 8 + q * 4);
          float4 g = *(const float4*)(dv + 8 + q * 4);
          hi[q * 4 + 0] = (short)f2bf(rintf(f.x) / g.x);
          hi[q * 4 + 1] = (short)f2bf(rintf(f.y) / g.y);
          hi[q * 4 + 2] = (short)f2bf(rintf(f.z) / g.z);
          hi[q * 4 + 3] = (short)f2bf(rintf(f.w) / g.w);
        }
      }
      if (c == 0) sP[r] = pe;
      *(short8*)&sX[r * SXS + c * 16] = lo;
      *(short8*)&sX[r * SXS + c * 16 + 8] = hi;
    }
    __syncthreads();

    // perm rows for this wave's L3 stores
    int prow[4];
#pragma unroll
    for (int rr = 0; rr < 4; ++rr) prow[rr] = (int)sP[w * 16 + kgrp * 4 + rr];

    // ---- layer 1: [64]->[128] relu, sX -> sH1 ----
#pragma unroll
    for (int rg = 0; rg < 4; ++rg) {
      short8 a0 = *(short8*)&sX[(rg * 16 + lrow) * SXS + kgrp * 8];
      short8 a1 = *(short8*)&sX[(rg * 16 + lrow) * SXS + 32 + kgrp * 8];
#pragma unroll
      for (int cb = 0; cb < 2; ++cb) {
        f32x4 acc = {sh0v[cb], sh0v[cb], sh0v[cb], sh0v[cb]};
        acc = __builtin_amdgcn_mfma_f32_16x16x32_bf16(a0, b0[cb][0], acc, 0, 0, 0);
        acc = __builtin_amdgcn_mfma_f32_16x16x32_bf16(a1, b0[cb][1], acc, 0, 0, 0);
#pragma unroll
        for (int rr = 0; rr < 4; ++rr)
          sH1[(rg * 16 + kgrp * 4 + rr) * SHS + (2 * w + cb) * 16 + lrow] =
              f2bf(fmaxf(acc[rr], 0.f));
      }
    }
    __syncthreads();

    // ---- layer 2: [128]->[128] relu, sH1 -> sH2 ----
#pragma unroll
    for (int rg = 0; rg < 4; ++rg) {
      short8 h0 = *(short8*)&sH1[(rg * 16 + lrow) * SHS + kgrp * 8];
      short8 h1 = *(short8*)&sH1[(rg * 16 + lrow) * SHS + 32 + kgrp * 8];
      short8 h2 = *(short8*)&sH1[(rg * 16 + lrow) * SHS + 64 + kgrp * 8];
      short8 h3 = *(short8*)&sH1[(rg * 16 + lrow) * SHS + 96 + kgrp * 8];
#pragma unroll
      for (int cb = 0; cb < 2; ++cb) {
        f32x4 acc = {sh1v[cb], sh1v[cb], sh1v[cb], sh1v[cb]};
        acc = __builtin_amdgcn_mfma_f32_16x16x32_bf16(h0, b1[cb][0], acc, 0, 0, 0);
        acc = __builtin_amdgcn_mfma_f32_16x16x32_bf16(h1, b1[cb][1], acc, 0, 0, 0);
        acc = __builtin_amdgcn_mfma_f32_16x16x32_bf16(h2, b1[cb][2], acc, 0, 0, 0);
        acc = __builtin_amdgcn_mfma_f32_16x16x32_bf16(h3, b1[cb][3], acc, 0, 0, 0);
#pragma unroll
        for (int rr = 0; rr < 4; ++rr)
          sH2[(rg * 16 + kgrp * 4 + rr) * SHS + (2 * w + cb) * 16 + lrow] =
              f2bf(fmaxf(acc[rr], 0.f));
      }
    }
    __syncthreads();

    // ---- layer 3: [128]->[16], row-group = wave, store via perm ----
    {
      short8 q0 = *(short8*)&sH2[(w * 16 + lrow) * SHS + kgrp * 8];
      short8 q1 = *(short8*)&sH2[(w * 16 + lrow) * SHS + 32 + kgrp * 8];
      short8 q2 = *(short8*)&sH2[(w * 16 + lrow) * SHS + 64 + kgrp * 8];
      short8 q3 = *(short8*)&sH2[(w * 16 + lrow) * SHS + 96 + kgrp * 8];
      f32x4 acc = {sh2v, sh2v, sh2v, sh2v};
      acc = __builtin_amdgcn_mfma_f32_16x16x32_bf16(q0, b2[0], acc, 0, 0, 0);
      acc = __builtin_amdgcn_mfma_f32_16x16x32_bf16(q1, b2[1], acc, 0, 0, 0);
      acc = __builtin_amdgcn_mfma_f32_16x16x32_bf16(q2, b2[2], acc, 0, 0, 0);
      acc = __builtin_amdgcn_mfma_f32_16x16x32_bf16(q3, b2[3], acc, 0, 0, 0);
#pragma unroll
      for (int rr = 0; rr < 4; ++rr) {
        int row = w * 16 + kgrp * 4 + rr;
        if (base + row < cnt) out[prow[rr] * FEATD + lrow] = acc[rr];
      }
    }
    __syncthreads();  // safety: sX/sP of next iteration never race L3 readers
  }
  }
}

// ---------------------------------------------------------------------------
extern "C" void kernel_launch(void* const* d_in, const int* in_sizes, int n_in,
                              void* d_out, int out_size, void* d_ws, size_t ws_size,
                              hipStream_t stream) {
  const float* weight      = (const float*)d_in[0];
  const float* alpha_param = (const float*)d_in[1];
  const float* divv        = (const float*)d_in[2];
  const float* scale0      = (const float*)d_in[3];
  const float* shift0      = (const float*)d_in[4];
  const float* scale1      = (const float*)d_in[5];
  const float* shift1      = (const float*)d_in[6];
  const float* scale2      = (const float*)d_in[7];
  const float* shift2      = (const float*)d_in[8];
  float* out = (float*)d_out;

  int* cursor = (int*)d_ws;                                   // [8]
  unsigned short* perm = (unsigned short*)((int*)d_ws + 8);   // [8][N]

  hipMemsetAsync(cursor, 0, DD * sizeof(int), stream);
  k_bucket<<<NN / 256, 256, 0, stream>>>(alpha_param, cursor, perm);
  k_mlp<<<DD * BPD, 256, 0, stream>>>(weight, divv,
                                      scale0, shift0, scale1, shift1,
                                      scale2, shift2,
                                      cursor, perm, out);
}

// Round 11
// 38.068 us; speedup vs baseline: 2.2867x; 1.6372x over previous
//
#include <hip/hip_runtime.h>

#define NN 65536
#define DD 8
#define LATD 64
#define HIDD 128
#define FEATD 16
#define BPD 96            // k_mlp blocks per decoder (768 total = 3/CU)
#define SXS 72            // sX stride (u16): 144 B = 9 quads (odd -> conflict-free)
#define SHS 136           // sH stride (u16): 272 B = 17 quads (odd -> conflict-free)

typedef __attribute__((ext_vector_type(8))) short short8;
typedef __attribute__((ext_vector_type(4))) float f32x4;

static __device__ __forceinline__ unsigned short f2bf(float f) {
  union { float f; unsigned u; } v; v.f = f;
  unsigned r = v.u + 0x7FFFu + ((v.u >> 16) & 1u);  // RNE; exact for small ints
  return (unsigned short)(r >> 16);
}

// ---- prep: blocks [0,256) bucket entries -> perm; [256,768) convert scales -
__global__ __launch_bounds__(256) void k_prep(
    const float* __restrict__ ap, int* __restrict__ cursor,
    unsigned short* __restrict__ perm,
    const float* __restrict__ s0, const float* __restrict__ s1,
    const float* __restrict__ s2, const float* __restrict__ divv,
    unsigned short* __restrict__ g0, unsigned short* __restrict__ g1,
    unsigned short* __restrict__ g2, float* __restrict__ rdiv) {
  int bid = blockIdx.x;
  int t = threadIdx.x;
  if (bid < 256) {
    __shared__ int bc[DD];
    __shared__ int bbase[DD];
    if (t < DD) bc[t] = 0;
    __syncthreads();
    int n = bid * 256 + t;
    float best = ap[n];
    int bd = 0;
#pragma unroll
    for (int d = 1; d < DD; ++d) {
      float v = ap[d * NN + n];
      if (v > best) { best = v; bd = d; }  // strict >: first max (jnp.argmax)
    }
    int lr = atomicAdd(&bc[bd], 1);
    __syncthreads();
    if (t < DD) bbase[t] = atomicAdd(&cursor[t], bc[t]);
    __syncthreads();
    perm[bd * NN + bbase[bd] + lr] = (unsigned short)n;
  } else {
    int o = (bid - 256) * 256 + t;
    if (o < DD * HIDD * LATD) {            // g0[d][n(128)][k(64)] <- s0[d][k][n]
      int d = o >> 13, rem = o & 8191, n = rem >> 6, k = rem & 63;
      g0[o] = f2bf(s0[d * 8192 + k * 128 + n]);
    }
    if (o < DD * HIDD * HIDD) {            // g1[d][n(128)][k(128)] <- s1[d][k][n]
      int d = o >> 14, rem = o & 16383, n = rem >> 7, k = rem & 127;
      g1[o] = f2bf(s1[d * 16384 + k * 128 + n]);
    }
    if (o < DD * FEATD * HIDD) {           // g2[d][n(16)][k(128)] <- s2[d][k][n]
      int d = o >> 11, rem = o & 2047, n = rem >> 7, k = rem & 127;
      g2[o] = f2bf(s2[d * 2048 + k * 16 + n]);
    }
    if (o < LATD) rdiv[o] = 1.0f / divv[o];
  }
}

// ---- gather: bandwidth-bound perm-order materialization of X as bf16 ------
// One thread per entry slot: random-read the 256B weight row, convert,
// write linear gx[rank][64]. 1024 waves x 16 outstanding loads => BW-bound.
__global__ __launch_bounds__(256) void k_gather(
    const float* __restrict__ weight, const float* __restrict__ rdiv,
    const int* __restrict__ cursor, const unsigned short* __restrict__ perm,
    unsigned short* __restrict__ gx) {
  int e = blockIdx.x * 256 + threadIdx.x;   // global rank 0..NN-1
  int off = 0, d = 0, acc = 0;
#pragma unroll
  for (int k = 0; k < DD - 1; ++k) {
    acc += cursor[k];
    if (e >= acc) { d = k + 1; off = acc; }
  }
  int entry = (int)perm[d * NN + (e - off)];
  const float* wr = weight + (size_t)entry * LATD;
  unsigned short* gr = gx + (size_t)e * LATD;
#pragma unroll
  for (int q = 0; q < 16; ++q) {
    float4 f = *(const float4*)(wr + q * 4);
    float4 g = *(const float4*)(rdiv + q * 4);
    unsigned short o0 = f2bf(rintf(f.x) * g.x);
    unsigned short o1 = f2bf(rintf(f.y) * g.y);
    unsigned short o2 = f2bf(rintf(f.z) * g.z);
    unsigned short o3 = f2bf(rintf(f.w) * g.w);
    *(ushort2*)(gr + q * 4) = make_ushort2(o0, o1);
    *(ushort2*)(gr + q * 4 + 2) = make_ushort2(o2, o3);
  }
}

// ---- fused 3-layer MFMA MLP (R10-proven sync skeleton) --------------------
// 256 thr = 4 waves; tile = 64 entries. Wave w owns output col-blocks
// {2w, 2w+1} for L1/L2; L3 row-group = w. Staging from gx (contiguous bf16)
// when use_gx, else champion gather-from-weight path.
__global__ __launch_bounds__(256, 3) void k_mlp(
    const float* __restrict__ weight, const float* __restrict__ rdiv,
    const unsigned short* __restrict__ g0, const float* __restrict__ sh0,
    const unsigned short* __restrict__ g1, const float* __restrict__ sh1,
    const unsigned short* __restrict__ g2, const float* __restrict__ sh2,
    const int* __restrict__ cursor, const unsigned short* __restrict__ perm,
    const unsigned short* __restrict__ gx, int use_gx,
    float* __restrict__ out) {
  __shared__ unsigned short sX[64 * SXS];   // X  [entry][k=64] bf16
  __shared__ unsigned short sH1[64 * SHS];  // H1 [entry][k=128] bf16
  __shared__ unsigned short sH2[64 * SHS];  // H2 [entry][k=128] bf16

  int d = blockIdx.x / BPD, bslot = blockIdx.x % BPD;
  int t = threadIdx.x;
  int w = t >> 6, l = t & 63;
  int lrow = l & 15, kgrp = l >> 4;

  int cnt = cursor[d];
  int offd = 0;
#pragma unroll
  for (int k = 0; k < DD - 1; ++k)
    if (k < d) offd += cursor[k];

  // ---- B fragments, contiguous bf16, once per block ----
  short8 b0[2][2];  // [cb][ks] layer1 (k=64)
  short8 b1[2][4];  // [cb][ks] layer2 (k=128)
  short8 b2[4];     // [ks]     layer3 (k=128, 16 cols)
  float sh0v[2], sh1v[2];
  {
    const unsigned short* G0 = g0 + d * (HIDD * LATD);
    const unsigned short* G1 = g1 + d * (HIDD * HIDD);
    const unsigned short* G2 = g2 + d * (FEATD * HIDD);
#pragma unroll
    for (int cb = 0; cb < 2; ++cb) {
      int n2 = (2 * w + cb) * 16 + lrow;
#pragma unroll
      for (int ks = 0; ks < 2; ++ks)
        b0[cb][ks] = *(const short8*)&G0[n2 * LATD + ks * 32 + kgrp * 8];
#pragma unroll
      for (int ks = 0; ks < 4; ++ks)
        b1[cb][ks] = *(const short8*)&G1[n2 * HIDD + ks * 32 + kgrp * 8];
      sh0v[cb] = sh0[d * HIDD + n2];
      sh1v[cb] = sh1[d * HIDD + n2];
    }
#pragma unroll
    for (int ks = 0; ks < 4; ++ks)
      b2[ks] = *(const short8*)&G2[lrow * HIDD + ks * 32 + kgrp * 8];
  }
  float sh2v = sh2[d * FEATD + lrow];

  for (int tile = bslot; tile * 64 < cnt; tile += BPD) {
    int base = tile * 64;

    // ---- stage X into sX ----
    if (use_gx) {
      // contiguous bf16 rows from gx (4 threads per row, 2 x dwordx4 each)
      int r = t >> 2, c = t & 3;
      int gp = base + r;
      short8 v0 = {0, 0, 0, 0, 0, 0, 0, 0}, v1 = {0, 0, 0, 0, 0, 0, 0, 0};
      if (gp < cnt) {
        const unsigned short* gr = gx + (size_t)(offd + gp) * LATD + c * 16;
        v0 = *(const short8*)gr;
        v1 = *(const short8*)(gr + 8);
      }
      *(short8*)&sX[r * SXS + c * 16] = v0;
      *(short8*)&sX[r * SXS + c * 16 + 8] = v1;
    } else {
      // fallback: gather from weight (champion path, rdiv multiply)
      int r = t >> 2, c = t & 3;
      int gp = base + r;
      short8 lo = {0, 0, 0, 0, 0, 0, 0, 0}, hi = {0, 0, 0, 0, 0, 0, 0, 0};
      if (gp < cnt) {
        int pe = (int)perm[d * NN + gp];
        const float* wr = weight + (size_t)pe * LATD + c * 16;
        const float* rd = rdiv + c * 16;
#pragma unroll
        for (int q = 0; q < 2; ++q) {
          float4 f = *(const float4*)(wr + q * 4);
          float4 g = *(const float4*)(rd + q * 4);
          lo[q * 4 + 0] = (short)f2bf(rintf(f.x) * g.x);
          lo[q * 4 + 1] = (short)f2bf(rintf(f.y) * g.y);
          lo[q * 4 + 2] = (short)f2bf(rintf(f.z) * g.z);
          lo[q * 4 + 3] = (short)f2bf(rintf(f.w) * g.w);
        }
#pragma unroll
        for (int q = 0; q < 2; ++q) {
          float4 f = *(const float4*)(wr + 8 + q * 4);
          float4 g = *(const float4*)(rd + 8 + q * 4);
          hi[q * 4 + 0] = (short)f2bf(rintf(f.x) * g.x);
          hi[q * 4 + 1] = (short)f2bf(rintf(f.y) * g.y);
          hi[q * 4 + 2] = (short)f2bf(rintf(f.z) * g.z);
          hi[q * 4 + 3] = (short)f2bf(rintf(f.w) * g.w);
        }
      }
      *(short8*)&sX[r * SXS + c * 16] = lo;
      *(short8*)&sX[r * SXS + c * 16 + 8] = hi;
    }

    // L3 store rows straight from global perm (L2-hot; no LDS dependency)
    int prow[4];
#pragma unroll
    for (int rr = 0; rr < 4; ++rr) {
      int row = w * 16 + kgrp * 4 + rr;
      prow[rr] = (base + row < cnt) ? (int)perm[d * NN + base + row] : 0;
    }
    __syncthreads();

    // ---- layer 1: [64]->[128] relu, sX -> sH1 ----
#pragma unroll
    for (int rg = 0; rg < 4; ++rg) {
      short8 a0 = *(short8*)&sX[(rg * 16 + lrow) * SXS + kgrp * 8];
      short8 a1 = *(short8*)&sX[(rg * 16 + lrow) * SXS + 32 + kgrp * 8];
#pragma unroll
      for (int cb = 0; cb < 2; ++cb) {
        f32x4 acc = {sh0v[cb], sh0v[cb], sh0v[cb], sh0v[cb]};
        acc = __builtin_amdgcn_mfma_f32_16x16x32_bf16(a0, b0[cb][0], acc, 0, 0, 0);
        acc = __builtin_amdgcn_mfma_f32_16x16x32_bf16(a1, b0[cb][1], acc, 0, 0, 0);
#pragma unroll
        for (int rr = 0; rr < 4; ++rr)
          sH1[(rg * 16 + kgrp * 4 + rr) * SHS + (2 * w + cb) * 16 + lrow] =
              f2bf(fmaxf(acc[rr], 0.f));
      }
    }
    __syncthreads();

    // ---- layer 2: [128]->[128] relu, sH1 -> sH2 ----
#pragma unroll
    for (int rg = 0; rg < 4; ++rg) {
      short8 h0 = *(short8*)&sH1[(rg * 16 + lrow) * SHS + kgrp * 8];
      short8 h1 = *(short8*)&sH1[(rg * 16 + lrow) * SHS + 32 + kgrp * 8];
      short8 h2 = *(short8*)&sH1[(rg * 16 + lrow) * SHS + 64 + kgrp * 8];
      short8 h3 = *(short8*)&sH1[(rg * 16 + lrow) * SHS + 96 + kgrp * 8];
#pragma unroll
      for (int cb = 0; cb < 2; ++cb) {
        f32x4 acc = {sh1v[cb], sh1v[cb], sh1v[cb], sh1v[cb]};
        acc = __builtin_amdgcn_mfma_f32_16x16x32_bf16(h0, b1[cb][0], acc, 0, 0, 0);
        acc = __builtin_amdgcn_mfma_f32_16x16x32_bf16(h1, b1[cb][1], acc, 0, 0, 0);
        acc = __builtin_amdgcn_mfma_f32_16x16x32_bf16(h2, b1[cb][2], acc, 0, 0, 0);
        acc = __builtin_amdgcn_mfma_f32_16x16x32_bf16(h3, b1[cb][3], acc, 0, 0, 0);
#pragma unroll
        for (int rr = 0; rr < 4; ++rr)
          sH2[(rg * 16 + kgrp * 4 + rr) * SHS + (2 * w + cb) * 16 + lrow] =
              f2bf(fmaxf(acc[rr], 0.f));
      }
    }
    __syncthreads();

    // ---- layer 3: [128]->[16], row-group = wave, store via perm ----
    {
      short8 q0 = *(short8*)&sH2[(w * 16 + lrow) * SHS + kgrp * 8];
      short8 q1 = *(short8*)&sH2[(w * 16 + lrow) * SHS + 32 + kgrp * 8];
      short8 q2 = *(short8*)&sH2[(w * 16 + lrow) * SHS + 64 + kgrp * 8];
      short8 q3 = *(short8*)&sH2[(w * 16 + lrow) * SHS + 96 + kgrp * 8];
      f32x4 acc = {sh2v, sh2v, sh2v, sh2v};
      acc = __builtin_amdgcn_mfma_f32_16x16x32_bf16(q0, b2[0], acc, 0, 0, 0);
      acc = __builtin_amdgcn_mfma_f32_16x16x32_bf16(q1, b2[1], acc, 0, 0, 0);
      acc = __builtin_amdgcn_mfma_f32_16x16x32_bf16(q2, b2[2], acc, 0, 0, 0);
      acc = __builtin_amdgcn_mfma_f32_16x16x32_bf16(q3, b2[3], acc, 0, 0, 0);
#pragma unroll
      for (int rr = 0; rr < 4; ++rr) {
        int row = w * 16 + kgrp * 4 + rr;
        if (base + row < cnt) out[prow[rr] * FEATD + lrow] = acc[rr];
      }
    }
    __syncthreads();  // replay-proven skeleton: next stage never races L3
  }
}

// ---------------------------------------------------------------------------
extern "C" void kernel_launch(void* const* d_in, const int* in_sizes, int n_in,
                              void* d_out, int out_size, void* d_ws, size_t ws_size,
                              hipStream_t stream) {
  const float* weight      = (const float*)d_in[0];
  const float* alpha_param = (const float*)d_in[1];
  const float* divv        = (const float*)d_in[2];
  const float* scale0      = (const float*)d_in[3];
  const float* shift0      = (const float*)d_in[4];
  const float* scale1      = (const float*)d_in[5];
  const float* shift1      = (const float*)d_in[6];
  const float* scale2      = (const float*)d_in[7];
  const float* shift2      = (const float*)d_in[8];
  float* out = (float*)d_out;

  char* ws = (char*)d_ws;
  int* cursor          = (int*)ws;                        // [8]      @0
  float* rdiv          = (float*)(ws + 256);              // [64]     @256
  unsigned short* perm = (unsigned short*)(ws + 512);     // [8][NN]  1MB
  unsigned short* g0   = perm + DD * NN;                  // 128K
  unsigned short* g1   = g0 + DD * HIDD * LATD;           // 256K
  unsigned short* g2   = g1 + DD * HIDD * HIDD;           // 32K
  unsigned short* gx   = g2 + DD * FEATD * HIDD;          // [NN][64] 8.4MB
  size_t need = (size_t)((char*)(gx + (size_t)NN * LATD) - ws);
  int use_gx = (ws_size >= need) ? 1 : 0;

  hipMemsetAsync(cursor, 0, DD * sizeof(int), stream);
  k_prep<<<768, 256, 0, stream>>>(alpha_param, cursor, perm,
                                  scale0, scale1, scale2, divv,
                                  g0, g1, g2, rdiv);
  if (use_gx)
    k_gather<<<NN / 256, 256, 0, stream>>>(weight, rdiv, cursor, perm, gx);
  k_mlp<<<DD * BPD, 256, 0, stream>>>(weight, rdiv,
                                      g0, shift0, g1, shift1, g2, shift2,
                                      cursor, perm, gx, use_gx, out);
}